// Round 1
// 89.398 us; speedup vs baseline: 1.0621x; 1.0621x over previous
//
#include <hip/hip_runtime.h>
#include <hip/hip_bf16.h>
#include <math.h>

#define B 8
#define F 256
#define L 2048
#define H 8
#define D 32
#define HD 256
#define W 6      // prior(6)=6e-9 -> band truncation ~1e-6; far field exact (exp(0)=1)
#define HALO 8   // halo rows each side of the 64-l tile -> M=80 rows
#define KST 264  // bf16 row stride (528 B): 256 data + 8 pad; even 32-bank spread
#define QST 260  // fp32 row stride (1040 B): 256 data + 4 pad; 260%32=4 -> even spread
                 // NOTE: previous kernel used stride 132 (<256!) -> Q rows collided in
                 // LDS ((l,hd) aliased (l+1,hd-132)); that was the absmax=4.0 source.

typedef __attribute__((ext_vector_type(8))) short bf16x8;
typedef __attribute__((ext_vector_type(4))) float f32x4;

__device__ __forceinline__ unsigned short f2bf_fast(float f) {
    union { float f; unsigned u; } v; v.f = f;
    return (unsigned short)((v.u + 0x8000u) >> 16);   // round-to-nearest, ties away
}
__device__ __forceinline__ float bf2f(unsigned u16) {
    union { unsigned u; float f; } v; v.u = u16 << 16;
    return v.f;
}

// ---------------------------------------------------------------------------
// prep_w: W[F,HD] fp32 -> Wt bf16 in FRAGMENT-MAJOR layout
//   Wt[((sel*16 + tile)*8 + ks)*64 + (quad*16 + lm)][j]  (8 bf16 per lane-frag)
//   holding W[f = ks*32 + quad*8 + j][hd = tile*16 + lm].
// A wave's B-fragment load in the fused kernel is then one contiguous 1 KiB burst.
// grid (8,32) = 256 blocks (was 32: latency-bound at 12% CU coverage).
//   x: sel = x>>2, hd-group = (x&3)*64;  y: f-group = y*8 (one (ks,quad) chunk).
// ---------------------------------------------------------------------------
__global__ __launch_bounds__(256) void prep_w_kernel(
    const float* __restrict__ Wq, const float* __restrict__ Wk,
    unsigned short* __restrict__ Wt)
{
    __shared__ unsigned short Ts[8][72];
    const int t   = threadIdx.x;
    const int sel = blockIdx.x >> 2;
    const int c0  = (blockIdx.x & 3) * 64;   // hd group
    const int r0  = blockIdx.y * 8;          // f group (8 rows = one ks/quad chunk)
    const float* __restrict__ src = sel ? Wk : Wq;
    unsigned short* __restrict__ dst = Wt + (size_t)sel * HD * F;

    if (t < 128) {
        int r  = t >> 4;          // 0..7
        int cb = (t & 15) * 4;    // 0..60
        float4 v = *(const float4*)&src[(size_t)(r0 + r) * HD + c0 + cb];
        Ts[r][cb + 0] = f2bf_fast(v.x);
        Ts[r][cb + 1] = f2bf_fast(v.y);
        Ts[r][cb + 2] = f2bf_fast(v.z);
        Ts[r][cb + 3] = f2bf_fast(v.w);
    }
    __syncthreads();
    if (t < 64) {
        const int hd   = c0 + t;
        const int tile = hd >> 4, lmw = hd & 15;
        const int ks   = r0 >> 5, qd  = (r0 >> 3) & 3;
        unsigned short tmp[8];
        #pragma unroll
        for (int j = 0; j < 8; ++j) tmp[j] = Ts[j][t];
        *(uint4*)&dst[(((size_t)tile * 8 + ks) * 64 + qd * 16 + lmw) * 8] =
            *(const uint4*)tmp;
    }
}

// ---------------------------------------------------------------------------
// fused: X-transpose (global->LDS bf16) + projection MFMA + banded attention.
// grid (32, 8) = 256 blocks = 1/CU, now 512 threads (8 waves = 2/SIMD for
// latency hiding; was 4 waves = 1/SIMD, fully latency-exposed).
//   phase 0: Xs[80][KST] bf16 <- x[b, :, l0-8 .. l0+71] (edge-clamped; clamped
//            halo rows are masked downstream, never consumed)
//   phase 1: af[5][8] frags from Xs (regs) | barrier (Xs dead) | 4 nt-tiles of
//            MFMA per wave with B-frags streamed coalesced from L2-hot Wt.
//            Waves 0-3 produce Q (fp32, stride-260 rows — collision-free),
//            waves 4-7 produce K (bf16). Qs aliases Xs region (83,200 B).
//   phase 2: banded softmax, W=6, far field closed-form. 1 output/thread.
// LDS total 125,440 B.
// ---------------------------------------------------------------------------
__global__ __launch_bounds__(512, 2) void fused_kernel(
    const float* __restrict__ x, const unsigned short* __restrict__ Wt,
    const float* __restrict__ bq, const float* __restrict__ bk,
    const float* __restrict__ pmean, const float* __restrict__ pstd,
    float* __restrict__ out)
{
    __shared__ uint4 smem4[7840];                          // 125,440 B
    unsigned short* Xs = (unsigned short*)smem4;           // [80][264] bf16 (dead after af)
    float*          Qs = (float*)smem4;                    // [80][260] fp32 (aliases Xs)
    unsigned short* Ks = (unsigned short*)(smem4 + 5200);  // [80][264] bf16 @ byte 83,200

    const int t    = threadIdx.x;
    const int l0   = blockIdx.x * 64;
    const int b    = blockIdx.y;
    const int lane = t & 63, wv = t >> 6;
    const int lm   = lane & 15, quad = lane >> 4;

    // ---- phase 0: stage Xs (transpose + cast) ----
    const float* __restrict__ xb = x + (size_t)b * F * L;
    #pragma unroll
    for (int i = 0; i < 10; ++i) {
        int idx = i * 512 + t;          // 5120 tasks: 80 l-rows x 64 f-chunks
        int lp  = idx % 80;
        int fg  = idx / 80;
        int m   = l0 - HALO + lp;
        m = min(max(m, 0), L - 1);      // edge clamp; clamped rows masked later
        unsigned p0, p1;
        {
            float v0 = xb[(size_t)(4 * fg + 0) * L + m];
            float v1 = xb[(size_t)(4 * fg + 1) * L + m];
            p0 = ((__float_as_uint(v0) + 0x8000u) >> 16) |
                 (((__float_as_uint(v1) + 0x8000u) >> 16) << 16);
            float v2 = xb[(size_t)(4 * fg + 2) * L + m];
            float v3 = xb[(size_t)(4 * fg + 3) * L + m];
            p1 = ((__float_as_uint(v2) + 0x8000u) >> 16) |
                 (((__float_as_uint(v3) + 0x8000u) >> 16) << 16);
        }
        uint2 pk; pk.x = p0; pk.y = p1;
        *(uint2*)&Xs[lp * KST + 4 * fg] = pk;
    }
    __syncthreads();

    // ---- A fragments into registers (160 VGPR), identical for every wave ----
    bf16x8 af[5][8];
    #pragma unroll
    for (int mt = 0; mt < 5; ++mt)
        #pragma unroll
        for (int ks = 0; ks < 8; ++ks)
            af[mt][ks] = *(const bf16x8*)&Xs[(mt * 16 + lm) * KST + ks * 32 + quad * 8];
    __syncthreads();   // all af reads drained before Qs overwrites Xs

    // ---- phase 1: MFMA nt-tiles (4 per wave; waves 0-3 -> Q, 4-7 -> K) ----
    #pragma unroll
    for (int nt = 0; nt < 4; ++nt) {
        const int hdq  = wv * 64 + nt * 16 + lm;   // 0..511
        const int sel  = hdq >> 8;                 // wave-uniform
        const int hd   = hdq & 255;
        const int tile = (hdq >> 4) & 15;          // wave-uniform
        // fragment-major Wt: this wave's ks-chunk loads are contiguous 1 KiB bursts
        const unsigned short* Bp =
            Wt + ((((size_t)sel * 16 + tile) * 8) * 64 + lane) * 8;
        f32x4 acc[5];
        #pragma unroll
        for (int mt = 0; mt < 5; ++mt) acc[mt] = (f32x4){0.f, 0.f, 0.f, 0.f};
        #pragma unroll
        for (int ks = 0; ks < 8; ++ks) {
            bf16x8 bfr = *(const bf16x8*)&Bp[ks * 512];
            #pragma unroll
            for (int mt = 0; mt < 5; ++mt)
                acc[mt] = __builtin_amdgcn_mfma_f32_16x16x32_bf16(
                    af[mt][ks], bfr, acc[mt], 0, 0, 0);
        }
        // C/D layout: col=lane&15 (=hd), row=quad*4+r (m89/m91-verified)
        float bv = sel ? bk[hd] : bq[hd];
        if (sel == 0) {
            #pragma unroll
            for (int mt = 0; mt < 5; ++mt)
                #pragma unroll
                for (int r = 0; r < 4; ++r)
                    Qs[(mt * 16 + quad * 4 + r) * QST + hd] = acc[mt][r] + bv;
        } else {
            #pragma unroll
            for (int mt = 0; mt < 5; ++mt)
                #pragma unroll
                for (int r = 0; r < 4; ++r)
                    Ks[(mt * 16 + quad * 4 + r) * KST + hd] = f2bf_fast(acc[mt][r] + bv);
        }
    }
    __syncthreads();

    // ---- phase 2: banded attention, one (l,h) output per thread ----
    const float mean = pmean[0];
    const float istd = 1.0f / pstd[0];
    const float cs   = 0.39894229f * istd * 0.17677670f;  // invsqrt2pi/std * D^-0.5
    float coef[2 * W + 1];
    #pragma unroll
    for (int j = 0; j <= 2 * W; ++j) {
        float z = ((float)(j - W) - mean) * istd;
        coef[j] = cs * __expf(-0.5f * z * z);
    }

    const int lp  = t & 63, h = t >> 6;
    const int l   = l0 + lp;
    const int row = lp + HALO;
    const float* qp = &Qs[row * QST + h * 32];
    float q[32];
    #pragma unroll
    for (int c = 0; c < 8; ++c) {
        float4 v = *(const float4*)&qp[c * 4];
        q[c * 4 + 0] = v.x; q[c * 4 + 1] = v.y;
        q[c * 4 + 2] = v.z; q[c * 4 + 3] = v.w;
    }
    float num = 0.f, den = 0.f, cnt = 0.f, dsum = 0.f;
    #pragma unroll
    for (int j = 0; j <= 2 * W; ++j) {
        const int dd = j - W;
        const int m  = l + dd;
        const unsigned short* kp = &Ks[(row + dd) * KST + h * 32];
        float dot = 0.f;
        #pragma unroll
        for (int c = 0; c < 4; ++c) {
            uint4 raw = *(const uint4*)&kp[c * 8];
            unsigned u[4] = {raw.x, raw.y, raw.z, raw.w};
            #pragma unroll
            for (int p = 0; p < 4; ++p) {
                dot = fmaf(q[c * 8 + p * 2],     bf2f(u[p] & 0xFFFFu), dot);
                dot = fmaf(q[c * 8 + p * 2 + 1], bf2f(u[p] >> 16),     dot);
            }
        }
        float e = __expf(dot * coef[j]);
        if (m >= 0 && m < L) {
            num = fmaf(e, (float)dd, num);
            den += e; cnt += 1.f; dsum += (float)dd;
        }
    }
    // far field: every out-of-band valid key contributes exp(0)=1 exactly
    float Sl = (float)(L * (L - 1) / 2 - L * l);   // exact in fp32
    out[((size_t)b * L + l) * H + h] =
        ((Sl - dsum) + num) / (((float)L - cnt) + den);
}

// ---------------------------------------------------------------------------
extern "C" void kernel_launch(void* const* d_in, const int* in_sizes, int n_in,
                              void* d_out, int out_size, void* d_ws, size_t ws_size,
                              hipStream_t stream) {
    const float* x  = (const float*)d_in[0];
    const float* Wq = (const float*)d_in[1];
    const float* bq = (const float*)d_in[2];
    const float* Wk = (const float*)d_in[3];
    const float* bk = (const float*)d_in[4];
    const float* pm = (const float*)d_in[5];
    const float* ps = (const float*)d_in[6];
    float* out = (float*)d_out;

    unsigned short* Wt = (unsigned short*)d_ws;    // 2*HD*F bf16 = 256 KB

    prep_w_kernel<<<dim3(8, 32), 256, 0, stream>>>(Wq, Wk, Wt);
    fused_kernel<<<dim3(L / 64, B), 512, 0, stream>>>(x, Wt, bq, bk, pm, ps, out);
}